// Round 5
// baseline (257.382 us; speedup 1.0000x reference)
//
#include <hip/hip_runtime.h>
#include <hip/hip_bf16.h>
#include <stdint.h>

// Fused causal attention block: qkv proj -> flash attention -> out proj.
// B=4 T=2048 C=1024 H=16 HD=64.  All MFMA 16x16x32 bf16, fp32 accum.
// Q is pre-scaled by 0.125*log2(e) in the qkv epilogue; softmax runs in
// base-2 domain (exp2f). Device-side dtype detection hedges fp32-vs-bf16.

typedef __attribute__((ext_vector_type(8))) short short8;
typedef __attribute__((ext_vector_type(4))) float f32x4;
typedef __attribute__((ext_vector_type(4))) float float4v;
typedef __attribute__((ext_vector_type(4))) unsigned short ushort4v;

#define AS1 __attribute__((address_space(1)))
#define AS3 __attribute__((address_space(3)))

static __device__ __forceinline__ void gload_lds16(const void* g, void* l) {
  __builtin_amdgcn_global_load_lds((const AS1 void*)g, (AS3 void*)l, 16, 0, 0);
}

// ---------------- dtype detect ----------------
__global__ void k_detect(const unsigned int* __restrict__ x, int* __restrict__ flag) {
  __shared__ int sm[256];
  int c = 0;
  for (int i = 0; i < 8; ++i) {
    unsigned int v = x[threadIdx.x * 8 + i];
    unsigned int e = (v >> 7) & 0xffu;
    if (e >= 110u && e <= 140u) c++;
  }
  sm[threadIdx.x] = c;
  __syncthreads();
  if (threadIdx.x == 0) {
    int t = 0;
    for (int i = 0; i < 256; ++i) t += sm[i];
    *flag = (t > 1024) ? 1 : 0;   // 1 = inputs are bf16, 0 = fp32
  }
}

// ---------------- fused convert: x | wqkv | wo -> contiguous bf16 ws ----------------
// element ranges: [0, 8388608) x, [8388608, 11534336) wqkv, [.., 12582912) wo.
// vectorized x4; all range boundaries divisible by 4.
__global__ void k_convert3(const void* __restrict__ xs, const void* __restrict__ wqs,
                           const void* __restrict__ wos, unsigned short* __restrict__ out,
                           const int* __restrict__ flag) {
  const int f = *flag;
  const int stride = gridDim.x * blockDim.x;
  for (int v = blockIdx.x * blockDim.x + threadIdx.x; v < 3145728; v += stride) {
    const int i = v * 4;
    const void* src; int j;
    if (i < 8388608)        { src = xs;  j = i; }
    else if (i < 11534336)  { src = wqs; j = i - 8388608; }
    else                    { src = wos; j = i - 11534336; }
    ushort4v r;
    if (f) {
      r = *(const ushort4v*)((const unsigned short*)src + j);
    } else {
      float4v fv = *(const float4v*)((const float*)src + j);
#pragma unroll
      for (int e = 0; e < 4; e++) {
        __hip_bfloat16 h = __float2bfloat16(fv[e]);
        r[e] = *(unsigned short*)&h;
      }
    }
    *(ushort4v*)(out + i) = r;
  }
}

// ---------------- stage 1: QKV GEMM ----------------
__global__ __launch_bounds__(256) void k_gemm_qkv(
    const __hip_bfloat16* __restrict__ X, const __hip_bfloat16* __restrict__ W,
    __hip_bfloat16* __restrict__ qo, __hip_bfloat16* __restrict__ ko,
    __hip_bfloat16* __restrict__ vto) {
  __shared__ __align__(16) __hip_bfloat16 As[128 * 32];
  __shared__ __align__(16) __hip_bfloat16 Bs[128 * 32];
  const int tid = threadIdx.x;
  const int lane = tid & 63;
  const int wid = tid >> 6;
  const int wr = wid >> 1, wc = wid & 1;
  const int lr = lane & 15, lk = lane >> 4;
  const int m0 = blockIdx.x * 128;
  const int n0 = blockIdx.y * 128;

  const f32x4 fzero = {0.f, 0.f, 0.f, 0.f};
  f32x4 acc[4][4];
#pragma unroll
  for (int i = 0; i < 4; i++)
#pragma unroll
    for (int j = 0; j < 4; j++) acc[i][j] = fzero;

  for (int kt = 0; kt < 32; ++kt) {
    const int k0 = kt * 32;
    __syncthreads();
#pragma unroll
    for (int j = 0; j < 2; ++j) {
      const int idx = j * 256 + tid;
      const int row = idx >> 2;
      const int ce = (idx & 3) * 8;
      gload_lds16(X + (size_t)(m0 + row) * 1024 + k0 + ce,
                  (void*)(As + (size_t)(j * 256 + (tid & ~63)) * 8));
      gload_lds16(W + (size_t)(n0 + row) * 1024 + k0 + ce,
                  (void*)(Bs + (size_t)(j * 256 + (tid & ~63)) * 8));
    }
    __syncthreads();
    short8 a[4], b[4];
#pragma unroll
    for (int i = 0; i < 4; i++) a[i] = *(const short8*)(As + (wr * 64 + i * 16 + lr) * 32 + lk * 8);
#pragma unroll
    for (int i = 0; i < 4; i++) b[i] = *(const short8*)(Bs + (wc * 64 + i * 16 + lr) * 32 + lk * 8);
#pragma unroll
    for (int mf = 0; mf < 4; mf++)
#pragma unroll
      for (int nf = 0; nf < 4; nf++)
        acc[mf][nf] = __builtin_amdgcn_mfma_f32_16x16x32_bf16(a[mf], b[nf], acc[mf][nf], 0, 0, 0);
  }
#pragma unroll
  for (int mf = 0; mf < 4; mf++)
#pragma unroll
    for (int nf = 0; nf < 4; nf++)
#pragma unroll
      for (int r = 0; r < 4; r++) {
        const int row = m0 + wr * 64 + mf * 16 + lk * 4 + r;  // b*T+t
        const int col = n0 + wc * 64 + nf * 16 + lr;          // [0,3072)
        const int s = col >> 10;
        const int rem = col & 1023;
        const int h = rem >> 6, hd = rem & 63;
        const int bb = row >> 11, t = row & 2047;
        const size_t bh = (size_t)(bb * 16 + h);
        if (s == 0) {
          // pre-scale Q by 0.125 * log2(e): softmax runs in base-2 domain
          qo[(bh * 2048 + t) * 64 + hd] = __float2bfloat16(acc[mf][nf][r] * 0.18033688f);
        } else if (s == 1) {
          ko[(bh * 2048 + t) * 64 + hd] = __float2bfloat16(acc[mf][nf][r]);
        } else {
          vto[(bh * 64 + hd) * 2048 + t] = __float2bfloat16(acc[mf][nf][r]);
        }
      }
}

// ---------------- stage 2: flash attention ----------------
// 512 blocks x 512 threads (8 waves). Q-tile 256 rows (32/wave). KV tile 64.
// bid layout: bh = bid&63 (XCD affinity), p = bid>>6 remapped so CU pairs
// (x, 7-x) -> constant per-CU work. K/V LDS double-buffered, gload_lds at
// loop top, 1 barrier/tile. XOR swizzle both-sides (rule 21).
// Softmax in base-2 domain (Q pre-scaled); l-reduction deferred to epilogue.
__global__ __launch_bounds__(512) void k_attn(
    const __hip_bfloat16* __restrict__ Q, const __hip_bfloat16* __restrict__ K,
    const __hip_bfloat16* __restrict__ VT, __hip_bfloat16* __restrict__ Y) {
  __shared__ __align__(16) __hip_bfloat16 Kl[2][64 * 64];
  __shared__ __align__(16) __hip_bfloat16 Vl[2][64 * 64];   // [d][key]
  __shared__ __align__(16) __hip_bfloat16 Pl[8][32 * 64];
  const int tid = threadIdx.x, lane = tid & 63, wid = tid >> 6;
  const int lr = lane & 15, lk = lane >> 4;

  const int bid = blockIdx.x;
  const int bh = bid & 63;
  const int p = bid >> 6;            // 0..7
  const int e = p & 3;
  const int x = (p < 4) ? p : 7 - e; // CU gets {e, 7-e}: 36 tiles constant
  const int q0 = x * 256;
  const int qb = q0 + wid * 32;
  const size_t base = (size_t)bh * 2048 * 64;

  // staging geometry: 512 chunks of 16B per 64x64 tile, 1 per thread
  const int srow = tid >> 3;                       // 0..63
  const int scol = ((tid & 7) ^ (srow & 7)) * 8;   // pre-swizzled source col
  const __hip_bfloat16* kg = K + base + scol;
  const __hip_bfloat16* vg = VT + base + (size_t)srow * 2048 + scol;

  short8 qf[2][2];
#pragma unroll
  for (int mf = 0; mf < 2; mf++)
#pragma unroll
    for (int ks = 0; ks < 2; ks++)
      qf[mf][ks] = *(const short8*)(Q + base + (size_t)(qb + mf * 16 + lr) * 64 + ks * 32 + lk * 8);

  const f32x4 fzero = {0.f, 0.f, 0.f, 0.f};
  f32x4 o[2][4];
  float mrow[2][4], lrow[2][4];
#pragma unroll
  for (int mf = 0; mf < 2; mf++) {
#pragma unroll
    for (int nf = 0; nf < 4; nf++) o[mf][nf] = fzero;
#pragma unroll
    for (int r = 0; r < 4; r++) { mrow[mf][r] = -1e30f; lrow[mf][r] = 0.f; }
  }

  const int nkv = x * 4 + 4;
  // prologue: stage tile 0 into buf 0
  gload_lds16(kg + (size_t)srow * 64, (void*)(&Kl[0][0] + (tid & ~63) * 8));
  gload_lds16(vg, (void*)(&Vl[0][0] + (tid & ~63) * 8));
  __syncthreads();   // drains vmcnt+lgkmcnt, joins waves

  int cur = 0;
  for (int kt = 0; kt < nkv; ++kt) {
    const int k0 = kt * 64;
    // issue next tile's loads first (latency hides under compute)
    if (kt + 1 < nkv) {
      const int kn = (kt + 1) * 64;
      gload_lds16(kg + (size_t)(kn + srow) * 64, (void*)(&Kl[cur ^ 1][0] + (tid & ~63) * 8));
      gload_lds16(vg + kn, (void*)(&Vl[cur ^ 1][0] + (tid & ~63) * 8));
    }

    if (k0 <= qb + 31) {   // wave-uniform: skip fully-masked tiles
      f32x4 s[2][4];
#pragma unroll
      for (int mf = 0; mf < 2; mf++)
#pragma unroll
        for (int nf = 0; nf < 4; nf++) s[mf][nf] = fzero;
      __builtin_amdgcn_s_setprio(1);
#pragma unroll
      for (int ks = 0; ks < 2; ks++) {
        short8 kb[4];
#pragma unroll
        for (int nf = 0; nf < 4; nf++) {
          const int r = nf * 16 + lr;
          kb[nf] = *(const short8*)(&Kl[cur][0] + r * 64 + (((ks * 4 + lk) ^ (r & 7)) * 8));
        }
#pragma unroll
        for (int mf = 0; mf < 2; mf++)
#pragma unroll
          for (int nf = 0; nf < 4; nf++)
            s[mf][nf] = __builtin_amdgcn_mfma_f32_16x16x32_bf16(qf[mf][ks], kb[nf], s[mf][nf], 0, 0, 0);
      }
      __builtin_amdgcn_s_setprio(0);

      const bool needmask = (k0 + 63 > qb);   // wave-uniform: diagonal tile?

      // online softmax, base-2 domain (acc layout: row = lk*4+r, col = lr)
#pragma unroll
      for (int mf = 0; mf < 2; mf++)
#pragma unroll
        for (int r = 0; r < 4; r++) {
          const int rowg = qb + mf * 16 + lk * 4 + r;
          const int pr = mf * 16 + lk * 4 + r;
          float mx = -1e30f;
          if (needmask) {
#pragma unroll
            for (int nf = 0; nf < 4; nf++) {
              float sv = s[mf][nf][r];
              if (k0 + nf * 16 + lr > rowg) sv = -1e30f;
              s[mf][nf][r] = sv;
              mx = fmaxf(mx, sv);
            }
          } else {
#pragma unroll
            for (int nf = 0; nf < 4; nf++) mx = fmaxf(mx, s[mf][nf][r]);
          }
#pragma unroll
          for (int d = 1; d < 16; d <<= 1) mx = fmaxf(mx, __shfl_xor(mx, d, 64));
          const float mold = mrow[mf][r];
          const float mnew = fmaxf(mold, mx);
          const float alpha = exp2f(mold - mnew);
          float rs = 0.f;
#pragma unroll
          for (int nf = 0; nf < 4; nf++) {
            const float pv = exp2f(s[mf][nf][r] - mnew);
            rs += pv;
            const int ce = nf * 16 + lr;
            Pl[wid][pr * 64 + (ce ^ ((pr & 7) << 3))] = __float2bfloat16(pv);
          }
          // per-lane partial row sum; cross-lane reduce deferred to epilogue
          lrow[mf][r] = lrow[mf][r] * alpha + rs;
          mrow[mf][r] = mnew;
#pragma unroll
          for (int nf = 0; nf < 4; nf++) o[mf][nf][r] *= alpha;
        }

      asm volatile("s_waitcnt lgkmcnt(0)" ::: "memory");
      __builtin_amdgcn_sched_barrier(0);

      // PV: A = P, B = V^T rows d (k = key contiguous)
      __builtin_amdgcn_s_setprio(1);
#pragma unroll
      for (int ks = 0; ks < 2; ks++) {
        short8 pa[2], vb[4];
#pragma unroll
        for (int mf = 0; mf < 2; mf++) {
          const int ar = mf * 16 + lr;
          pa[mf] = *(const short8*)(&Pl[wid][0] + ar * 64 + (((ks * 4 + lk) ^ (ar & 7)) * 8));
        }
#pragma unroll
        for (int nf = 0; nf < 4; nf++) {
          const int d = nf * 16 + lr;
          vb[nf] = *(const short8*)(&Vl[cur][0] + d * 64 + (((ks * 4 + lk) ^ (d & 7)) * 8));
        }
#pragma unroll
        for (int mf = 0; mf < 2; mf++)
#pragma unroll
          for (int nf = 0; nf < 4; nf++)
            o[mf][nf] = __builtin_amdgcn_mfma_f32_16x16x32_bf16(pa[mf], vb[nf], o[mf][nf], 0, 0, 0);
      }
      __builtin_amdgcn_s_setprio(0);
    }

    // single barrier per tile: drains own gloads (issued pre-compute ->
    // latency hidden) and joins waves before buffer flip.
    __syncthreads();
    cur ^= 1;
  }

  const int b = bh >> 4, h = bh & 15;
#pragma unroll
  for (int mf = 0; mf < 2; mf++)
#pragma unroll
    for (int r = 0; r < 4; r++) {
      // deferred l reduction: sum per-lane partials across the 16-lane group
      float ls = lrow[mf][r];
#pragma unroll
      for (int d = 1; d < 16; d <<= 1) ls += __shfl_xor(ls, d, 64);
      const float inv = 1.f / ls;
      const int t = qb + mf * 16 + lk * 4 + r;
#pragma unroll
      for (int nf = 0; nf < 4; nf++)
        Y[((size_t)b * 2048 + t) * 1024 + h * 64 + nf * 16 + lr] =
            __float2bfloat16(o[mf][nf][r] * inv);
    }
}

// ---------------- stage 3: output GEMM ----------------
__global__ __launch_bounds__(256) void k_gemm_out(
    const __hip_bfloat16* __restrict__ X, const __hip_bfloat16* __restrict__ W,
    void* __restrict__ out, const int* __restrict__ flag) {
  __shared__ __align__(16) __hip_bfloat16 As[128 * 32];
  __shared__ __align__(16) __hip_bfloat16 Bs[128 * 32];
  const int tid = threadIdx.x;
  const int lane = tid & 63;
  const int wid = tid >> 6;
  const int wr = wid >> 1, wc = wid & 1;
  const int lr = lane & 15, lk = lane >> 4;
  const int m0 = blockIdx.x * 128;
  const int n0 = blockIdx.y * 128;

  const f32x4 fzero = {0.f, 0.f, 0.f, 0.f};
  f32x4 acc[4][4];
#pragma unroll
  for (int i = 0; i < 4; i++)
#pragma unroll
    for (int j = 0; j < 4; j++) acc[i][j] = fzero;

  for (int kt = 0; kt < 32; ++kt) {
    const int k0 = kt * 32;
    __syncthreads();
#pragma unroll
    for (int j = 0; j < 2; ++j) {
      const int idx = j * 256 + tid;
      const int row = idx >> 2;
      const int ce = (idx & 3) * 8;
      gload_lds16(X + (size_t)(m0 + row) * 1024 + k0 + ce,
                  (void*)(As + (size_t)(j * 256 + (tid & ~63)) * 8));
      gload_lds16(W + (size_t)(n0 + row) * 1024 + k0 + ce,
                  (void*)(Bs + (size_t)(j * 256 + (tid & ~63)) * 8));
    }
    __syncthreads();
    short8 a[4], b[4];
#pragma unroll
    for (int i = 0; i < 4; i++) a[i] = *(const short8*)(As + (wr * 64 + i * 16 + lr) * 32 + lk * 8);
#pragma unroll
    for (int i = 0; i < 4; i++) b[i] = *(const short8*)(Bs + (wc * 64 + i * 16 + lr) * 32 + lk * 8);
#pragma unroll
    for (int mf = 0; mf < 4; mf++)
#pragma unroll
      for (int nf = 0; nf < 4; nf++)
        acc[mf][nf] = __builtin_amdgcn_mfma_f32_16x16x32_bf16(a[mf], b[nf], acc[mf][nf], 0, 0, 0);
  }
  const int f = *flag;
#pragma unroll
  for (int mf = 0; mf < 4; mf++)
#pragma unroll
    for (int nf = 0; nf < 4; nf++)
#pragma unroll
      for (int r = 0; r < 4; r++) {
        const int row = m0 + wr * 64 + mf * 16 + lk * 4 + r;
        const int col = n0 + wc * 64 + nf * 16 + lr;
        const size_t oi = (size_t)row * 1024 + col;
        if (f) ((__hip_bfloat16*)out)[oi] = __float2bfloat16(acc[mf][nf][r]);
        else   ((float*)out)[oi] = acc[mf][nf][r];
      }
}

// ---------------- launch ----------------
extern "C" void kernel_launch(void* const* d_in, const int* in_sizes, int n_in,
                              void* d_out, int out_size, void* d_ws, size_t ws_size,
                              hipStream_t stream) {
  const void* x = d_in[0];     // [4,2048,1024]
  const void* wqkv = d_in[1];  // [3072,1024]
  const void* wo = d_in[2];    // [1024,1024]

  char* ws = (char*)d_ws;
  int* flag = (int*)ws;
  __hip_bfloat16* xb    = (__hip_bfloat16*)(ws + 256);
  __hip_bfloat16* wqkvb = xb + 8388608;
  __hip_bfloat16* wob   = wqkvb + 3145728;
  __hip_bfloat16* qws   = wob + 1048576;
  __hip_bfloat16* kws   = qws + 8388608;   // 64*2048*64
  __hip_bfloat16* vtws  = kws + 8388608;
  __hip_bfloat16* yws   = xb;              // alias: xb dead after QKV GEMM
  // peak ws use: ~72 MB

  k_detect<<<1, 256, 0, stream>>>((const unsigned int*)x, flag);
  k_convert3<<<2048, 256, 0, stream>>>(x, wqkv, wo, (unsigned short*)xb, flag);

  dim3 g1(64, 24);
  k_gemm_qkv<<<g1, 256, 0, stream>>>(xb, wqkvb, qws, kws, vtws);

  k_attn<<<512, 512, 0, stream>>>(qws, kws, vtws, yws);

  dim3 g3(64, 8);
  k_gemm_out<<<g3, 256, 0, stream>>>(yws, wob, d_out, flag);
}

// Round 6
// 250.672 us; speedup vs baseline: 1.0268x; 1.0268x over previous
//
#include <hip/hip_runtime.h>
#include <hip/hip_bf16.h>
#include <stdint.h>

// Fused causal attention block: qkv proj -> flash attention -> out proj.
// B=4 T=2048 C=1024 H=16 HD=64.  All MFMA 16x16x32 bf16, fp32 accum.
// Q is pre-scaled by 0.125*log2(e) in the qkv epilogue; softmax runs in
// base-2 domain via raw v_exp_f32. Defer-rescale (T13, THR=8).

typedef __attribute__((ext_vector_type(8))) short short8;
typedef __attribute__((ext_vector_type(4))) float f32x4;
typedef __attribute__((ext_vector_type(4))) float float4v;
typedef __attribute__((ext_vector_type(4))) unsigned short ushort4v;

#define AS1 __attribute__((address_space(1)))
#define AS3 __attribute__((address_space(3)))

#if __has_builtin(__builtin_amdgcn_exp2f)
#define EXP2(x) __builtin_amdgcn_exp2f(x)
#else
#define EXP2(x) __expf((x) * 0.69314718f)
#endif

static __device__ __forceinline__ void gload_lds16(const void* g, void* l) {
  __builtin_amdgcn_global_load_lds((const AS1 void*)g, (AS3 void*)l, 16, 0, 0);
}

// ---------------- dtype detect ----------------
__global__ void k_detect(const unsigned int* __restrict__ x, int* __restrict__ flag) {
  __shared__ int sm[256];
  int c = 0;
  for (int i = 0; i < 8; ++i) {
    unsigned int v = x[threadIdx.x * 8 + i];
    unsigned int e = (v >> 7) & 0xffu;
    if (e >= 110u && e <= 140u) c++;
  }
  sm[threadIdx.x] = c;
  __syncthreads();
  if (threadIdx.x == 0) {
    int t = 0;
    for (int i = 0; i < 256; ++i) t += sm[i];
    *flag = (t > 1024) ? 1 : 0;   // 1 = inputs are bf16, 0 = fp32
  }
}

// ---------------- fused convert: x | wqkv | wo -> contiguous bf16 ws ----------------
__global__ void k_convert3(const void* __restrict__ xs, const void* __restrict__ wqs,
                           const void* __restrict__ wos, unsigned short* __restrict__ out,
                           const int* __restrict__ flag) {
  const int f = *flag;
  const int stride = gridDim.x * blockDim.x;
  for (int v = blockIdx.x * blockDim.x + threadIdx.x; v < 3145728; v += stride) {
    const int i = v * 4;
    const void* src; int j;
    if (i < 8388608)        { src = xs;  j = i; }
    else if (i < 11534336)  { src = wqs; j = i - 8388608; }
    else                    { src = wos; j = i - 11534336; }
    ushort4v r;
    if (f) {
      r = *(const ushort4v*)((const unsigned short*)src + j);
    } else {
      float4v fv = *(const float4v*)((const float*)src + j);
#pragma unroll
      for (int e = 0; e < 4; e++) {
        __hip_bfloat16 h = __float2bfloat16(fv[e]);
        r[e] = *(unsigned short*)&h;
      }
    }
    *(ushort4v*)(out + i) = r;
  }
}

// ---------------- stage 1: QKV GEMM ----------------
__global__ __launch_bounds__(256) void k_gemm_qkv(
    const __hip_bfloat16* __restrict__ X, const __hip_bfloat16* __restrict__ W,
    __hip_bfloat16* __restrict__ qo, __hip_bfloat16* __restrict__ ko,
    __hip_bfloat16* __restrict__ vto) {
  __shared__ __align__(16) __hip_bfloat16 As[128 * 32];
  __shared__ __align__(16) __hip_bfloat16 Bs[128 * 32];
  const int tid = threadIdx.x;
  const int lane = tid & 63;
  const int wid = tid >> 6;
  const int wr = wid >> 1, wc = wid & 1;
  const int lr = lane & 15, lk = lane >> 4;
  const int m0 = blockIdx.x * 128;
  const int n0 = blockIdx.y * 128;

  const f32x4 fzero = {0.f, 0.f, 0.f, 0.f};
  f32x4 acc[4][4];
#pragma unroll
  for (int i = 0; i < 4; i++)
#pragma unroll
    for (int j = 0; j < 4; j++) acc[i][j] = fzero;

  for (int kt = 0; kt < 32; ++kt) {
    const int k0 = kt * 32;
    __syncthreads();
#pragma unroll
    for (int j = 0; j < 2; ++j) {
      const int idx = j * 256 + tid;
      const int row = idx >> 2;
      const int ce = (idx & 3) * 8;
      gload_lds16(X + (size_t)(m0 + row) * 1024 + k0 + ce,
                  (void*)(As + (size_t)(j * 256 + (tid & ~63)) * 8));
      gload_lds16(W + (size_t)(n0 + row) * 1024 + k0 + ce,
                  (void*)(Bs + (size_t)(j * 256 + (tid & ~63)) * 8));
    }
    __syncthreads();
    short8 a[4], b[4];
#pragma unroll
    for (int i = 0; i < 4; i++) a[i] = *(const short8*)(As + (wr * 64 + i * 16 + lr) * 32 + lk * 8);
#pragma unroll
    for (int i = 0; i < 4; i++) b[i] = *(const short8*)(Bs + (wc * 64 + i * 16 + lr) * 32 + lk * 8);
#pragma unroll
    for (int mf = 0; mf < 4; mf++)
#pragma unroll
      for (int nf = 0; nf < 4; nf++)
        acc[mf][nf] = __builtin_amdgcn_mfma_f32_16x16x32_bf16(a[mf], b[nf], acc[mf][nf], 0, 0, 0);
  }
#pragma unroll
  for (int mf = 0; mf < 4; mf++)
#pragma unroll
    for (int nf = 0; nf < 4; nf++)
#pragma unroll
      for (int r = 0; r < 4; r++) {
        const int row = m0 + wr * 64 + mf * 16 + lk * 4 + r;  // b*T+t
        const int col = n0 + wc * 64 + nf * 16 + lr;          // [0,3072)
        const int s = col >> 10;
        const int rem = col & 1023;
        const int h = rem >> 6, hd = rem & 63;
        const int bb = row >> 11, t = row & 2047;
        const size_t bh = (size_t)(bb * 16 + h);
        if (s == 0) {
          // pre-scale Q by 0.125 * log2(e): softmax runs in base-2 domain
          qo[(bh * 2048 + t) * 64 + hd] = __float2bfloat16(acc[mf][nf][r] * 0.18033688f);
        } else if (s == 1) {
          ko[(bh * 2048 + t) * 64 + hd] = __float2bfloat16(acc[mf][nf][r]);
        } else {
          vto[(bh * 64 + hd) * 2048 + t] = __float2bfloat16(acc[mf][nf][r]);
        }
      }
}

// ---------------- stage 2: flash attention ----------------
// 512 blocks x 512 threads (8 waves). Q-tile 256 rows (32/wave). KV tile 64.
// bid layout: bh = bid&63 (XCD affinity), p = bid>>6 remapped so CU pairs
// (x, 7-x) -> constant per-CU work. K/V LDS double-buffered, gload_lds at
// loop top, 1 barrier/tile. XOR swizzle both-sides (rule 21).
// Base-2 softmax (raw v_exp_f32), deferred l-reduction, T13 defer-rescale.
__global__ __launch_bounds__(512) void k_attn(
    const __hip_bfloat16* __restrict__ Q, const __hip_bfloat16* __restrict__ K,
    const __hip_bfloat16* __restrict__ VT, __hip_bfloat16* __restrict__ Y) {
  __shared__ __align__(16) __hip_bfloat16 Kl[2][64 * 64];
  __shared__ __align__(16) __hip_bfloat16 Vl[2][64 * 64];   // [d][key]
  __shared__ __align__(16) __hip_bfloat16 Pl[8][32 * 64];
  const int tid = threadIdx.x, lane = tid & 63, wid = tid >> 6;
  const int lr = lane & 15, lk = lane >> 4;

  const int bid = blockIdx.x;
  const int bh = bid & 63;
  const int p = bid >> 6;            // 0..7
  const int e = p & 3;
  const int x = (p < 4) ? p : 7 - e; // CU gets {e, 7-e}: 36 tiles constant
  const int q0 = x * 256;
  const int qb = q0 + wid * 32;
  const size_t base = (size_t)bh * 2048 * 64;

  // staging geometry: 512 chunks of 16B per 64x64 tile, 1 per thread
  const int srow = tid >> 3;                       // 0..63
  const int scol = ((tid & 7) ^ (srow & 7)) * 8;   // pre-swizzled source col
  const __hip_bfloat16* kg = K + base + scol;
  const __hip_bfloat16* vg = VT + base + (size_t)srow * 2048 + scol;

  short8 qf[2][2];
#pragma unroll
  for (int mf = 0; mf < 2; mf++)
#pragma unroll
    for (int ks = 0; ks < 2; ks++)
      qf[mf][ks] = *(const short8*)(Q + base + (size_t)(qb + mf * 16 + lr) * 64 + ks * 32 + lk * 8);

  const f32x4 fzero = {0.f, 0.f, 0.f, 0.f};
  f32x4 o[2][4];
  float mrow[2][4], lrow[2][4];
#pragma unroll
  for (int mf = 0; mf < 2; mf++) {
#pragma unroll
    for (int nf = 0; nf < 4; nf++) o[mf][nf] = fzero;
#pragma unroll
    for (int r = 0; r < 4; r++) { mrow[mf][r] = -1e30f; lrow[mf][r] = 0.f; }
  }

  const int nkv = x * 4 + 4;
  // prologue: stage tile 0 into buf 0
  gload_lds16(kg + (size_t)srow * 64, (void*)(&Kl[0][0] + (tid & ~63) * 8));
  gload_lds16(vg, (void*)(&Vl[0][0] + (tid & ~63) * 8));
  __syncthreads();   // drains vmcnt+lgkmcnt, joins waves

  int cur = 0;
  for (int kt = 0; kt < nkv; ++kt) {
    const int k0 = kt * 64;
    // issue next tile's loads first (latency hides under compute)
    if (kt + 1 < nkv) {
      const int kn = (kt + 1) * 64;
      gload_lds16(kg + (size_t)(kn + srow) * 64, (void*)(&Kl[cur ^ 1][0] + (tid & ~63) * 8));
      gload_lds16(vg + kn, (void*)(&Vl[cur ^ 1][0] + (tid & ~63) * 8));
    }

    if (k0 <= qb + 31) {   // wave-uniform: skip fully-masked tiles
      f32x4 s[2][4];
#pragma unroll
      for (int mf = 0; mf < 2; mf++)
#pragma unroll
        for (int nf = 0; nf < 4; nf++) s[mf][nf] = fzero;
      __builtin_amdgcn_s_setprio(1);
#pragma unroll
      for (int ks = 0; ks < 2; ks++) {
        short8 kb[4];
#pragma unroll
        for (int nf = 0; nf < 4; nf++) {
          const int r = nf * 16 + lr;
          kb[nf] = *(const short8*)(&Kl[cur][0] + r * 64 + (((ks * 4 + lk) ^ (r & 7)) * 8));
        }
#pragma unroll
        for (int mf = 0; mf < 2; mf++)
#pragma unroll
          for (int nf = 0; nf < 4; nf++)
            s[mf][nf] = __builtin_amdgcn_mfma_f32_16x16x32_bf16(qf[mf][ks], kb[nf], s[mf][nf], 0, 0, 0);
      }
      __builtin_amdgcn_s_setprio(0);

      const bool needmask = (k0 + 63 > qb);   // wave-uniform: diagonal tile?

      // online softmax, base-2 domain (acc layout: row = lk*4+r, col = lr)
#pragma unroll
      for (int mf = 0; mf < 2; mf++)
#pragma unroll
        for (int r = 0; r < 4; r++) {
          const int rowg = qb + mf * 16 + lk * 4 + r;
          const int pr = mf * 16 + lk * 4 + r;
          float mx = -1e30f;
          if (needmask) {
#pragma unroll
            for (int nf = 0; nf < 4; nf++) {
              float sv = s[mf][nf][r];
              if (k0 + nf * 16 + lr > rowg) sv = -1e30f;
              s[mf][nf][r] = sv;
              mx = fmaxf(mx, sv);
            }
          } else {
#pragma unroll
            for (int nf = 0; nf < 4; nf++) mx = fmaxf(mx, s[mf][nf][r]);
          }
#pragma unroll
          for (int d = 1; d < 16; d <<= 1) mx = fmaxf(mx, __shfl_xor(mx, d, 64));
          const float mold = mrow[mf][r];
          float rs = 0.f;
          if (__all(mx - mold <= 8.f)) {
            // T13 defer: keep old max, skip rescale (P bounded by 2^8)
#pragma unroll
            for (int nf = 0; nf < 4; nf++) {
              const float pv = EXP2(s[mf][nf][r] - mold);
              rs += pv;
              const int ce = nf * 16 + lr;
              Pl[wid][pr * 64 + (ce ^ ((pr & 7) << 3))] = __float2bfloat16(pv);
            }
            lrow[mf][r] += rs;
          } else {
            const float mnew = fmaxf(mold, mx);
            const float alpha = EXP2(mold - mnew);
#pragma unroll
            for (int nf = 0; nf < 4; nf++) {
              const float pv = EXP2(s[mf][nf][r] - mnew);
              rs += pv;
              const int ce = nf * 16 + lr;
              Pl[wid][pr * 64 + (ce ^ ((pr & 7) << 3))] = __float2bfloat16(pv);
            }
            lrow[mf][r] = lrow[mf][r] * alpha + rs;
            mrow[mf][r] = mnew;
#pragma unroll
            for (int nf = 0; nf < 4; nf++) o[mf][nf][r] *= alpha;
          }
        }

      asm volatile("s_waitcnt lgkmcnt(0)" ::: "memory");
      __builtin_amdgcn_sched_barrier(0);

      // PV: A = P, B = V^T rows d (k = key contiguous)
      __builtin_amdgcn_s_setprio(1);
#pragma unroll
      for (int ks = 0; ks < 2; ks++) {
        short8 pa[2], vb[4];
#pragma unroll
        for (int mf = 0; mf < 2; mf++) {
          const int ar = mf * 16 + lr;
          pa[mf] = *(const short8*)(&Pl[wid][0] + ar * 64 + (((ks * 4 + lk) ^ (ar & 7)) * 8));
        }
#pragma unroll
        for (int nf = 0; nf < 4; nf++) {
          const int d = nf * 16 + lr;
          vb[nf] = *(const short8*)(&Vl[cur][0] + d * 64 + (((ks * 4 + lk) ^ (d & 7)) * 8));
        }
#pragma unroll
        for (int mf = 0; mf < 2; mf++)
#pragma unroll
          for (int nf = 0; nf < 4; nf++)
            o[mf][nf] = __builtin_amdgcn_mfma_f32_16x16x32_bf16(pa[mf], vb[nf], o[mf][nf], 0, 0, 0);
      }
      __builtin_amdgcn_s_setprio(0);
    }

    // single barrier per tile: drains own gloads (issued pre-compute ->
    // latency hidden) and joins waves before buffer flip.
    __syncthreads();
    cur ^= 1;
  }

  const int b = bh >> 4, h = bh & 15;
#pragma unroll
  for (int mf = 0; mf < 2; mf++)
#pragma unroll
    for (int r = 0; r < 4; r++) {
      // deferred l reduction: sum per-lane partials across the 16-lane group
      float ls = lrow[mf][r];
#pragma unroll
      for (int d = 1; d < 16; d <<= 1) ls += __shfl_xor(ls, d, 64);
      const float inv = 1.f / ls;
      const int t = qb + mf * 16 + lk * 4 + r;
#pragma unroll
      for (int nf = 0; nf < 4; nf++)
        Y[((size_t)b * 2048 + t) * 1024 + h * 64 + nf * 16 + lr] =
            __float2bfloat16(o[mf][nf][r] * inv);
    }
}

// ---------------- stage 3: output GEMM ----------------
__global__ __launch_bounds__(256) void k_gemm_out(
    const __hip_bfloat16* __restrict__ X, const __hip_bfloat16* __restrict__ W,
    void* __restrict__ out, const int* __restrict__ flag) {
  __shared__ __align__(16) __hip_bfloat16 As[128 * 32];
  __shared__ __align__(16) __hip_bfloat16 Bs[128 * 32];
  const int tid = threadIdx.x;
  const int lane = tid & 63;
  const int wid = tid >> 6;
  const int wr = wid >> 1, wc = wid & 1;
  const int lr = lane & 15, lk = lane >> 4;
  const int m0 = blockIdx.x * 128;
  const int n0 = blockIdx.y * 128;

  const f32x4 fzero = {0.f, 0.f, 0.f, 0.f};
  f32x4 acc[4][4];
#pragma unroll
  for (int i = 0; i < 4; i++)
#pragma unroll
    for (int j = 0; j < 4; j++) acc[i][j] = fzero;

  for (int kt = 0; kt < 32; ++kt) {
    const int k0 = kt * 32;
    __syncthreads();
#pragma unroll
    for (int j = 0; j < 2; ++j) {
      const int idx = j * 256 + tid;
      const int row = idx >> 2;
      const int ce = (idx & 3) * 8;
      gload_lds16(X + (size_t)(m0 + row) * 1024 + k0 + ce,
                  (void*)(As + (size_t)(j * 256 + (tid & ~63)) * 8));
      gload_lds16(W + (size_t)(n0 + row) * 1024 + k0 + ce,
                  (void*)(Bs + (size_t)(j * 256 + (tid & ~63)) * 8));
    }
    __syncthreads();
    short8 a[4], b[4];
#pragma unroll
    for (int i = 0; i < 4; i++) a[i] = *(const short8*)(As + (wr * 64 + i * 16 + lr) * 32 + lk * 8);
#pragma unroll
    for (int i = 0; i < 4; i++) b[i] = *(const short8*)(Bs + (wc * 64 + i * 16 + lr) * 32 + lk * 8);
#pragma unroll
    for (int mf = 0; mf < 4; mf++)
#pragma unroll
      for (int nf = 0; nf < 4; nf++)
        acc[mf][nf] = __builtin_amdgcn_mfma_f32_16x16x32_bf16(a[mf], b[nf], acc[mf][nf], 0, 0, 0);
  }
  const int f = *flag;
#pragma unroll
  for (int mf = 0; mf < 4; mf++)
#pragma unroll
    for (int nf = 0; nf < 4; nf++)
#pragma unroll
      for (int r = 0; r < 4; r++) {
        const int row = m0 + wr * 64 + mf * 16 + lk * 4 + r;
        const int col = n0 + wc * 64 + nf * 16 + lr;
        const size_t oi = (size_t)row * 1024 + col;
        if (f) ((__hip_bfloat16*)out)[oi] = __float2bfloat16(acc[mf][nf][r]);
        else   ((float*)out)[oi] = acc[mf][nf][r];
      }
}

// ---------------- launch ----------------
extern "C" void kernel_launch(void* const* d_in, const int* in_sizes, int n_in,
                              void* d_out, int out_size, void* d_ws, size_t ws_size,
                              hipStream_t stream) {
  const void* x = d_in[0];     // [4,2048,1024]
  const void* wqkv = d_in[1];  // [3072,1024]
  const void* wo = d_in[2];    // [1024,1024]

  char* ws = (char*)d_ws;
  int* flag = (int*)ws;
  __hip_bfloat16* xb    = (__hip_bfloat16*)(ws + 256);
  __hip_bfloat16* wqkvb = xb + 8388608;
  __hip_bfloat16* wob   = wqkvb + 3145728;
  __hip_bfloat16* qws   = wob + 1048576;
  __hip_bfloat16* kws   = qws + 8388608;   // 64*2048*64
  __hip_bfloat16* vtws  = kws + 8388608;
  __hip_bfloat16* yws   = xb;              // alias: xb dead after QKV GEMM
  // peak ws use: ~72 MB

  k_detect<<<1, 256, 0, stream>>>((const unsigned int*)x, flag);
  k_convert3<<<2048, 256, 0, stream>>>(x, wqkv, wo, (unsigned short*)xb, flag);

  dim3 g1(64, 24);
  k_gemm_qkv<<<g1, 256, 0, stream>>>(xb, wqkvb, qws, kws, vtws);

  k_attn<<<512, 512, 0, stream>>>(qws, kws, vtws, yws);

  dim3 g3(64, 8);
  k_gemm_out<<<g3, 256, 0, stream>>>(yws, wob, d_out, flag);
}